// Round 18
// baseline (134.114 us; speedup 1.0000x reference)
//
#include <hip/hip_runtime.h>

// Bidirectional LSTM, B=16384 T=512 I=1 H=8, + final linear on [h_f(T-1), h_b(T-1)].
// Backward direction's state at time T-1 is its FIRST scan step -> one step only.
//
// R18 = R16 (zero-DS packed broadcast + fdot2 dots + ILP-2, sequential A;B
// steps, compiler-scheduled) with gate activations moved OFF the trans pipe:
//  - 1024-segment PWL sigmoid LUT in LDS (R3-validated table). Table coordinate
//    u = 32*z + 512 (64*g + 512 for tanh row) folded into the fdot2 weights and
//    biases, so the dot product directly yields the coordinate.
//  - Per element-step: 4 ds_read_b64 gathers + 4 fma replace 4 v_exp + 2 v_rcp.
//    Trans 7 -> 2 (only the serial cell-tanh exp+rcp remain). R16 ledger: trans
//    was 224 of 419 busy cyc/SIMD-step at 16 cyc/instr (quarter-rate wave64).
//  - Why now and not R3: R3 was chain-latency-bound (LUT added DS latency to
//    the serial chain). R16 is ISSUE-bound with an idle DS pipe, and element
//    B's 40-instr dot cluster covers element A's gather latency (counted
//    lgkmcnt), unlike R10's wave-wide swizzle waits inside the chain.
//  - tanh(g) = 2*sigma(2g)-1; cell stays pre-scaled by 2log2e so tanh(c)'s
//    exp argument is the cell register itself.

#define LOG2E 1.4426950408889634f

typedef __fp16 h2 __attribute__((ext_vector_type(2)));

// DPP move of a float: ctrl 0x141 = row_half_mirror (8-lane-group preserving)
#define DPPF(v, ctrl) __int_as_float(__builtin_amdgcn_update_dpp(0, __float_as_int(v), (ctrl), 0xF, 0xF, true))
// DPP move of a packed h2 (32-bit): quad_perm broadcast k = k*0x55
#define DPPQH(v, k) __builtin_bit_cast(h2, __builtin_amdgcn_update_dpp(0, __builtin_bit_cast(int, (v)), ((k) * 0x55), 0xF, 0xF, true))

struct Ctx {
    h2 wi2[4], wf2[4], wg2[4], wo2[4];  // pair-packed f16, scaled to table coords
    float xi, xf, xg, xo;               // input weights, coord-scaled (f32)
    float bi, bf, bg, bo;               // biases, coord-scaled + 512 (f32)
};

__device__ __forceinline__ void load_ctx(Ctx& C, int j, int qp,
    const float* __restrict__ w_ih, const float* __restrict__ w_hh,
    const float* __restrict__ b)
{
    const float si = 32.0f;            // sigma rows: u = 32*z + 512
    const float sg = 64.0f;            // tanh row:   u = 64*g + 512 (-> sigma(2g))

    const float* ri = w_hh + (size_t)j * 8;
    const float* rf = w_hh + (size_t)(8 + j) * 8;
    const float* rg = w_hh + (size_t)(16 + j) * 8;
    const float* ro = w_hh + (size_t)(24 + j) * 8;
#pragma unroll
    for (int p = 0; p < 4; ++p) {
        int s0 = 4 * qp + p;           // pair element 0: own-quad value
        int s1 = 7 - 4 * qp - p;       // pair element 1: mirrored value
        C.wi2[p] = h2{(__fp16)(ri[s0] * si), (__fp16)(ri[s1] * si)};
        C.wf2[p] = h2{(__fp16)(rf[s0] * si), (__fp16)(rf[s1] * si)};
        C.wg2[p] = h2{(__fp16)(rg[s0] * sg), (__fp16)(rg[s1] * sg)};
        C.wo2[p] = h2{(__fp16)(ro[s0] * si), (__fp16)(ro[s1] * si)};
    }
    C.xi = w_ih[j] * si;      C.bi = fmaf(b[j], si, 512.0f);
    C.xf = w_ih[8 + j] * si;  C.bf = fmaf(b[8 + j], si, 512.0f);
    C.xg = w_ih[16 + j] * sg; C.bg = fmaf(b[16 + j], sg, 512.0f);
    C.xo = w_ih[24 + j] * si; C.bo = fmaf(b[24 + j], si, 512.0f);
}

// PWL sigmoid lookup; u is the table coordinate; entry = {slope, intercept}.
__device__ __forceinline__ float lut_sig(const float2* __restrict__ t, float u) {
    float uc = __builtin_amdgcn_fmed3f(u, 0.0f, 1023.0f);
    int i = (int)uc;
    float2 si = t[i];
    return fmaf(si.x, uc, si.y);
}

// One LSTM step for one element. cs pre-scaled by 2*log2(e).
__device__ __forceinline__ void lstm_step1(float xt, float& h, float& cs,
                                           const Ctx& C, const float2* __restrict__ tab)
{
    float hm = DPPF(h, 0x141);                    // h[7-(i&7)] within 8-group
    h2 ph = __builtin_amdgcn_cvt_pkrtz(h, hm);    // {h_l, h_mirror(l)} packed
    h2 p0 = DPPQH(ph, 0);
    h2 p1 = DPPQH(ph, 1);
    h2 p2 = DPPQH(ph, 2);
    h2 p3 = DPPQH(ph, 3);

    float ui = fmaf(xt, C.xi, C.bi);
    float uf = fmaf(xt, C.xf, C.bf);
    float ug = fmaf(xt, C.xg, C.bg);
    float uo = fmaf(xt, C.xo, C.bo);
    ui = __builtin_amdgcn_fdot2(p0, C.wi2[0], ui, false);
    uf = __builtin_amdgcn_fdot2(p0, C.wf2[0], uf, false);
    ug = __builtin_amdgcn_fdot2(p0, C.wg2[0], ug, false);
    uo = __builtin_amdgcn_fdot2(p0, C.wo2[0], uo, false);
    ui = __builtin_amdgcn_fdot2(p1, C.wi2[1], ui, false);
    uf = __builtin_amdgcn_fdot2(p1, C.wf2[1], uf, false);
    ug = __builtin_amdgcn_fdot2(p1, C.wg2[1], ug, false);
    uo = __builtin_amdgcn_fdot2(p1, C.wo2[1], uo, false);
    ui = __builtin_amdgcn_fdot2(p2, C.wi2[2], ui, false);
    uf = __builtin_amdgcn_fdot2(p2, C.wf2[2], uf, false);
    ug = __builtin_amdgcn_fdot2(p2, C.wg2[2], ug, false);
    uo = __builtin_amdgcn_fdot2(p2, C.wo2[2], uo, false);
    ui = __builtin_amdgcn_fdot2(p3, C.wi2[3], ui, false);
    uf = __builtin_amdgcn_fdot2(p3, C.wf2[3], uf, false);
    ug = __builtin_amdgcn_fdot2(p3, C.wg2[3], ug, false);
    uo = __builtin_amdgcn_fdot2(p3, C.wo2[3], uo, false);

    // LDS gathers (DS pipe; latency hidden by the other element's stream)
    float sigi = lut_sig(tab, ui);
    float sigf = lut_sig(tab, uf);
    float sg2  = lut_sig(tab, ug);    // sigma(2g)
    float sigo = lut_sig(tab, uo);

    // tgs = 2log2e * tanh(g) = 4log2e*sigma(2g) - 2log2e
    float tgs = fmaf(4.0f * LOG2E, sg2, -2.0f * LOG2E);
    cs = fmaf(sigf, cs, sigi * tgs);
    // tanh(c) = 1 - 2/(1+e^{2c}); e^{2c} = exp2(cs)  [only trans ops left]
    float ec = __builtin_amdgcn_exp2f(cs);
    float qc = __builtin_amdgcn_rcpf(1.0f + ec);
    h = sigo * fmaf(-2.0f, qc, 1.0f);
}

__global__ __launch_bounds__(256, 1) void bilstm_kernel(
    const float* __restrict__ x, const float* __restrict__ h0, const float* __restrict__ c0,
    const float* __restrict__ w_ih_f, const float* __restrict__ w_hh_f, const float* __restrict__ b_f,
    const float* __restrict__ w_ih_b, const float* __restrict__ w_hh_b, const float* __restrict__ b_b,
    const float* __restrict__ w_lin, const float* __restrict__ b_lin,
    float* __restrict__ out, int B, int T)
{
    __shared__ float2 tab[1024];
    // PWL sigmoid table: node i at x = (i-512)/32; f(u) = slope*u + intercept.
    for (int i = threadIdx.x; i < 1024; i += 256) {
        float x0 = (i - 512) * (1.0f / 32.0f);
        float x1 = (i - 511) * (1.0f / 32.0f);
        float s0 = 1.0f / (1.0f + __expf(-x0));
        float s1 = 1.0f / (1.0f + __expf(-x1));
        float slope = s1 - s0;  // per index unit
        tab[i] = make_float2(slope, fmaf(-slope, (float)i, s0));
    }
    __syncthreads();

    int tid = blockIdx.x * 256 + threadIdx.x;
    int p = tid >> 3;                  // element-pair index
    int j = tid & 7;
    int qp = (threadIdx.x >> 2) & 1;   // quad parity within the 8-lane group
    if (p >= (B >> 1)) return;
    int e0 = 2 * p, e1 = 2 * p + 1;

    Ctx Cf;
    load_ctx(Cf, j, qp, w_ih_f, w_hh_f, b_f);

    float hA  = h0[(size_t)e0 * 8 + j];
    float hB  = h0[(size_t)e1 * 8 + j];
    float csA = c0[(size_t)e0 * 8 + j] * (2.0f * LOG2E);
    float csB = c0[(size_t)e1 * 8 + j] * (2.0f * LOG2E);

    const float4* xrA = (const float4*)(x + (size_t)e0 * T);
    const float4* xrB = (const float4*)(x + (size_t)e1 * T);
    int nT4 = T >> 2;
    float4 xvA = xrA[0];
    float4 xvB = xrB[0];
    // software pipeline: load group t4+1 unconditionally, use group t4
    for (int t4 = 0; t4 < nT4 - 1; ++t4) {
        float4 nA = xrA[t4 + 1];
        float4 nB = xrB[t4 + 1];
        lstm_step1(xvA.x, hA, csA, Cf, tab); lstm_step1(xvB.x, hB, csB, Cf, tab);
        lstm_step1(xvA.y, hA, csA, Cf, tab); lstm_step1(xvB.y, hB, csB, Cf, tab);
        lstm_step1(xvA.z, hA, csA, Cf, tab); lstm_step1(xvB.z, hB, csB, Cf, tab);
        lstm_step1(xvA.w, hA, csA, Cf, tab); lstm_step1(xvB.w, hB, csB, Cf, tab);
        xvA = nA; xvB = nB;
    }
    // epilogue: last group
    lstm_step1(xvA.x, hA, csA, Cf, tab); lstm_step1(xvB.x, hB, csB, Cf, tab);
    lstm_step1(xvA.y, hA, csA, Cf, tab); lstm_step1(xvB.y, hB, csB, Cf, tab);
    lstm_step1(xvA.z, hA, csA, Cf, tab); lstm_step1(xvB.z, hB, csB, Cf, tab);
    float xlastA = xvA.w, xlastB = xvB.w;
    lstm_step1(xlastA, hA, csA, Cf, tab); lstm_step1(xlastB, hB, csB, Cf, tab);

    // backward direction: exactly one step on x[:, T-1]
    Ctx Cb;
    load_ctx(Cb, j, qp, w_ih_b, w_hh_b, b_b);
    float hbA  = h0[(size_t)B * 8 + (size_t)e0 * 8 + j];
    float hbB  = h0[(size_t)B * 8 + (size_t)e1 * 8 + j];
    float cbA  = c0[(size_t)B * 8 + (size_t)e0 * 8 + j] * (2.0f * LOG2E);
    float cbB  = c0[(size_t)B * 8 + (size_t)e1 * 8 + j] * (2.0f * LOG2E);
    lstm_step1(xlastA, hbA, cbA, Cb, tab);
    lstm_step1(xlastB, hbB, cbB, Cb, tab);

    // final linear per element, reduced across the 8-lane group
    float pA = fmaf(hA, w_lin[j], hbA * w_lin[8 + j]);
    float pB = fmaf(hB, w_lin[j], hbB * w_lin[8 + j]);
    pA += __shfl_xor(pA, 1, 8);
    pB += __shfl_xor(pB, 1, 8);
    pA += __shfl_xor(pA, 2, 8);
    pB += __shfl_xor(pB, 2, 8);
    pA += __shfl_xor(pA, 4, 8);
    pB += __shfl_xor(pB, 4, 8);
    if (j == 0) {
        float bl = b_lin[0];
        out[e0] = pA + bl;
        out[e1] = pB + bl;
    }
}

extern "C" void kernel_launch(void* const* d_in, const int* in_sizes, int n_in,
                              void* d_out, int out_size, void* d_ws, size_t ws_size,
                              hipStream_t stream)
{
    const float* x      = (const float*)d_in[0];
    const float* h0     = (const float*)d_in[1];
    const float* c0     = (const float*)d_in[2];
    const float* w_ih_f = (const float*)d_in[3];
    const float* w_hh_f = (const float*)d_in[4];
    const float* b_f    = (const float*)d_in[5];
    const float* w_ih_b = (const float*)d_in[6];
    const float* w_hh_b = (const float*)d_in[7];
    const float* b_b    = (const float*)d_in[8];
    const float* w_lin  = (const float*)d_in[9];
    const float* b_lin  = (const float*)d_in[10];
    float* out = (float*)d_out;

    int B = in_sizes[1] / 16;   // h0: (2, B, 8)
    int T = in_sizes[0] / B;    // x:  (B, T, 1)

    int threads = (B / 2) * 8;
    dim3 block(256);
    dim3 grid((threads + 255) / 256);
    hipLaunchKernelGGL(bilstm_kernel, grid, block, 0, stream,
                       x, h0, c0, w_ih_f, w_hh_f, b_f, w_ih_b, w_hh_b, b_b,
                       w_lin, b_lin, out, B, T);
}

// Round 19
// 105.164 us; speedup vs baseline: 1.2753x; 1.2753x over previous
//
#include <hip/hip_runtime.h>

// Bidirectional LSTM, B=16384 T=512 I=1 H=8, + final linear on [h_f(T-1), h_b(T-1)].
// Backward direction's state at time T-1 is its FIRST scan step -> one step only.
//
// R19 = R16 restored (best verified: 105.2 us). The two orthogonal follow-ups
// both regressed and are reverted:
//   R17 manual half-step stagger: -6% (live-range growth; compiler already
//       interleaves the sequential A;B blocks optimally).
//   R18 LDS-LUT gate activations: -27% (1 wave/SIMD -> lgkmcnt waits are
//       wave-wide and serialize both element streams).
// Structure: 8 lanes/element, ILP-2 (two independent batch elements/thread,
// 1024 waves = 1 wave/SIMD), zero-DS packed broadcast (1 row_half_mirror DPP +
// 1 cvt_pkrtz + 4 quad_perm DPP on the packed pair), fdot2 gate dots with
// pair-packed f16 weights (shared by both elements), ONE rcp for 4 gates,
// activation scales folded into weights, cell pre-scaled by 2log2e,
// unconditional software-pipelined x prefetch.
// Ledger at this point: 576 cyc/SIMD-step wall = 419 busy (96 reg VALU x2 +
// 14 trans x16.2 quarter-rate) + 157 chain stall. Trans count, FMA count,
// broadcast ops, and occupancy configuration are each at their measured or
// arithmetic minimum for this decomposition.

#define LOG2E 1.4426950408889634f

typedef __fp16 h2 __attribute__((ext_vector_type(2)));

// DPP move of a float: ctrl 0x141 = row_half_mirror (8-lane-group preserving)
#define DPPF(v, ctrl) __int_as_float(__builtin_amdgcn_update_dpp(0, __float_as_int(v), (ctrl), 0xF, 0xF, true))
// DPP move of a packed h2 (32-bit): quad_perm broadcast k = k*0x55
#define DPPQH(v, k) __builtin_bit_cast(h2, __builtin_amdgcn_update_dpp(0, __builtin_bit_cast(int, (v)), ((k) * 0x55), 0xF, 0xF, true))

struct Ctx {
    h2 wi2[4], wf2[4], wg2[4], wo2[4];  // pre-scaled, pair-packed to DPP delivery
    float xi, xf, xg, xo;               // input weights, pre-scaled (f32)
    float bi, bf, bg, bo;               // biases, pre-scaled (f32)
};

__device__ __forceinline__ void load_ctx(Ctx& C, int j, int qp,
    const float* __restrict__ w_ih, const float* __restrict__ w_hh,
    const float* __restrict__ b)
{
    const float si = -LOG2E;           // sigma rows: e = exp2(-z*log2e) = e^-z
    const float sg = 2.0f * LOG2E;     // tanh row:  e = exp2(2z*log2e) = e^{2z}

    const float* ri = w_hh + (size_t)j * 8;
    const float* rf = w_hh + (size_t)(8 + j) * 8;
    const float* rg = w_hh + (size_t)(16 + j) * 8;
    const float* ro = w_hh + (size_t)(24 + j) * 8;
#pragma unroll
    for (int p = 0; p < 4; ++p) {
        int s0 = 4 * qp + p;           // pair element 0: own-quad value
        int s1 = 7 - 4 * qp - p;       // pair element 1: mirrored value
        C.wi2[p] = h2{(__fp16)(ri[s0] * si), (__fp16)(ri[s1] * si)};
        C.wf2[p] = h2{(__fp16)(rf[s0] * si), (__fp16)(rf[s1] * si)};
        C.wg2[p] = h2{(__fp16)(rg[s0] * sg), (__fp16)(rg[s1] * sg)};
        C.wo2[p] = h2{(__fp16)(ro[s0] * si), (__fp16)(ro[s1] * si)};
    }
    C.xi = w_ih[j] * si;      C.bi = b[j] * si;
    C.xf = w_ih[8 + j] * si;  C.bf = b[8 + j] * si;
    C.xg = w_ih[16 + j] * sg; C.bg = b[16 + j] * sg;
    C.xo = w_ih[24 + j] * si; C.bo = b[24 + j] * si;
}

// One LSTM step for one element (all-VALU; no DS).
__device__ __forceinline__ void lstm_step1(float xt, float& h, float& cs, const Ctx& C)
{
    float hm = DPPF(h, 0x141);                    // h[7-(i&7)] within 8-group
    h2 ph = __builtin_amdgcn_cvt_pkrtz(h, hm);    // {h_l, h_mirror(l)} packed
    h2 p0 = DPPQH(ph, 0);
    h2 p1 = DPPQH(ph, 1);
    h2 p2 = DPPQH(ph, 2);
    h2 p3 = DPPQH(ph, 3);

    float zi = fmaf(xt, C.xi, C.bi);
    float zf = fmaf(xt, C.xf, C.bf);
    float zg = fmaf(xt, C.xg, C.bg);
    float zo = fmaf(xt, C.xo, C.bo);
    zi = __builtin_amdgcn_fdot2(p0, C.wi2[0], zi, false);
    zf = __builtin_amdgcn_fdot2(p0, C.wf2[0], zf, false);
    zg = __builtin_amdgcn_fdot2(p0, C.wg2[0], zg, false);
    zo = __builtin_amdgcn_fdot2(p0, C.wo2[0], zo, false);
    zi = __builtin_amdgcn_fdot2(p1, C.wi2[1], zi, false);
    zf = __builtin_amdgcn_fdot2(p1, C.wf2[1], zf, false);
    zg = __builtin_amdgcn_fdot2(p1, C.wg2[1], zg, false);
    zo = __builtin_amdgcn_fdot2(p1, C.wo2[1], zo, false);
    zi = __builtin_amdgcn_fdot2(p2, C.wi2[2], zi, false);
    zf = __builtin_amdgcn_fdot2(p2, C.wf2[2], zf, false);
    zg = __builtin_amdgcn_fdot2(p2, C.wg2[2], zg, false);
    zo = __builtin_amdgcn_fdot2(p2, C.wo2[2], zo, false);
    zi = __builtin_amdgcn_fdot2(p3, C.wi2[3], zi, false);
    zf = __builtin_amdgcn_fdot2(p3, C.wf2[3], zf, false);
    zg = __builtin_amdgcn_fdot2(p3, C.wg2[3], zg, false);
    zo = __builtin_amdgcn_fdot2(p3, C.wo2[3], zo, false);

    float eg = __builtin_amdgcn_exp2f(zg);   // e^{2g}
    float ei = __builtin_amdgcn_exp2f(zi);   // e^{-i}
    float ef = __builtin_amdgcn_exp2f(zf);   // e^{-f}
    float eo = __builtin_amdgcn_exp2f(zo);   // e^{-o}
    float di = 1.0f + ei, df = 1.0f + ef;
    float dg = 1.0f + eg, dz = 1.0f + eo;

    float d12 = di * df;
    float d34 = dg * dz;
    float R = __builtin_amdgcn_rcpf(d12 * d34);
    float t34 = R * d34;                     // 1/(di*df)
    float t12 = R * d12;                     // 1/(dg*dz)
    float sigi = t34 * df;                   // sigma(i)
    float sigf = t34 * di;                   // sigma(f)
    float qg   = t12 * dz;                   // 1/(1+e^{2g})
    float sigo = t12 * dg;                   // sigma(o)

    float tgs = fmaf(-4.0f * LOG2E, qg, 2.0f * LOG2E);   // 2log2e * tanh(g)
    cs = fmaf(sigf, cs, sigi * tgs);
    float ec = __builtin_amdgcn_exp2f(cs);
    float qc = __builtin_amdgcn_rcpf(1.0f + ec);
    h = sigo * fmaf(-2.0f, qc, 1.0f);
}

__global__ __launch_bounds__(256, 1) void bilstm_kernel(
    const float* __restrict__ x, const float* __restrict__ h0, const float* __restrict__ c0,
    const float* __restrict__ w_ih_f, const float* __restrict__ w_hh_f, const float* __restrict__ b_f,
    const float* __restrict__ w_ih_b, const float* __restrict__ w_hh_b, const float* __restrict__ b_b,
    const float* __restrict__ w_lin, const float* __restrict__ b_lin,
    float* __restrict__ out, int B, int T)
{
    int tid = blockIdx.x * 256 + threadIdx.x;
    int p = tid >> 3;                  // element-pair index
    int j = tid & 7;
    int qp = (threadIdx.x >> 2) & 1;   // quad parity within the 8-lane group
    if (p >= (B >> 1)) return;
    int e0 = 2 * p, e1 = 2 * p + 1;

    Ctx Cf;
    load_ctx(Cf, j, qp, w_ih_f, w_hh_f, b_f);

    float hA  = h0[(size_t)e0 * 8 + j];
    float hB  = h0[(size_t)e1 * 8 + j];
    float csA = c0[(size_t)e0 * 8 + j] * (2.0f * LOG2E);
    float csB = c0[(size_t)e1 * 8 + j] * (2.0f * LOG2E);

    const float4* xrA = (const float4*)(x + (size_t)e0 * T);
    const float4* xrB = (const float4*)(x + (size_t)e1 * T);
    int nT4 = T >> 2;
    float4 xvA = xrA[0];
    float4 xvB = xrB[0];
    // software pipeline: load group t4+1 unconditionally, use group t4
    for (int t4 = 0; t4 < nT4 - 1; ++t4) {
        float4 nA = xrA[t4 + 1];
        float4 nB = xrB[t4 + 1];
        lstm_step1(xvA.x, hA, csA, Cf); lstm_step1(xvB.x, hB, csB, Cf);
        lstm_step1(xvA.y, hA, csA, Cf); lstm_step1(xvB.y, hB, csB, Cf);
        lstm_step1(xvA.z, hA, csA, Cf); lstm_step1(xvB.z, hB, csB, Cf);
        lstm_step1(xvA.w, hA, csA, Cf); lstm_step1(xvB.w, hB, csB, Cf);
        xvA = nA; xvB = nB;
    }
    // epilogue: last group
    lstm_step1(xvA.x, hA, csA, Cf); lstm_step1(xvB.x, hB, csB, Cf);
    lstm_step1(xvA.y, hA, csA, Cf); lstm_step1(xvB.y, hB, csB, Cf);
    lstm_step1(xvA.z, hA, csA, Cf); lstm_step1(xvB.z, hB, csB, Cf);
    float xlastA = xvA.w, xlastB = xvB.w;
    lstm_step1(xlastA, hA, csA, Cf); lstm_step1(xlastB, hB, csB, Cf);

    // backward direction: exactly one step on x[:, T-1]
    Ctx Cb;
    load_ctx(Cb, j, qp, w_ih_b, w_hh_b, b_b);
    float hbA  = h0[(size_t)B * 8 + (size_t)e0 * 8 + j];
    float hbB  = h0[(size_t)B * 8 + (size_t)e1 * 8 + j];
    float cbA  = c0[(size_t)B * 8 + (size_t)e0 * 8 + j] * (2.0f * LOG2E);
    float cbB  = c0[(size_t)B * 8 + (size_t)e1 * 8 + j] * (2.0f * LOG2E);
    lstm_step1(xlastA, hbA, cbA, Cb);
    lstm_step1(xlastB, hbB, cbB, Cb);

    // final linear per element, reduced across the 8-lane group
    float pA = fmaf(hA, w_lin[j], hbA * w_lin[8 + j]);
    float pB = fmaf(hB, w_lin[j], hbB * w_lin[8 + j]);
    pA += __shfl_xor(pA, 1, 8);
    pB += __shfl_xor(pB, 1, 8);
    pA += __shfl_xor(pA, 2, 8);
    pB += __shfl_xor(pB, 2, 8);
    pA += __shfl_xor(pA, 4, 8);
    pB += __shfl_xor(pB, 4, 8);
    if (j == 0) {
        float bl = b_lin[0];
        out[e0] = pA + bl;
        out[e1] = pB + bl;
    }
}

extern "C" void kernel_launch(void* const* d_in, const int* in_sizes, int n_in,
                              void* d_out, int out_size, void* d_ws, size_t ws_size,
                              hipStream_t stream)
{
    const float* x      = (const float*)d_in[0];
    const float* h0     = (const float*)d_in[1];
    const float* c0     = (const float*)d_in[2];
    const float* w_ih_f = (const float*)d_in[3];
    const float* w_hh_f = (const float*)d_in[4];
    const float* b_f    = (const float*)d_in[5];
    const float* w_ih_b = (const float*)d_in[6];
    const float* w_hh_b = (const float*)d_in[7];
    const float* b_b    = (const float*)d_in[8];
    const float* w_lin  = (const float*)d_in[9];
    const float* b_lin  = (const float*)d_in[10];
    float* out = (float*)d_out;

    int B = in_sizes[1] / 16;   // h0: (2, B, 8)
    int T = in_sizes[0] / B;    // x:  (B, T, 1)

    int threads = (B / 2) * 8;
    dim3 block(256);
    dim3 grid((threads + 255) / 256);
    hipLaunchKernelGGL(bilstm_kernel, grid, block, 0, stream,
                       x, h0, c0, w_ih_f, w_hh_f, b_f, w_ih_b, w_hh_b, b_b,
                       w_lin, b_lin, out, B, T);
}